// Round 6
// baseline (129.628 us; speedup 1.0000x reference)
//
#include <hip/hip_runtime.h>
#include <hip/hip_bf16.h>
#include <cstdint>
#include <cstddef>

#define IN_F   1024
#define OUT_F  1024
#define NB     8            // KNOT_COUNT + ORDER = 5 + 3
#define BATCH  4096
#define KTOT   (NB * IN_F)  // 8192

typedef __attribute__((ext_vector_type(4)))  float  f32x4;
typedef __attribute__((ext_vector_type(8)))  float  f32x8;
typedef __attribute__((ext_vector_type(16))) float  f32x16;
typedef __attribute__((ext_vector_type(8)))  __bf16 bf16x8;
typedef __attribute__((ext_vector_type(4)))  unsigned short u16x4;

// async global->LDS, 16B per lane (LDS dest = wave-uniform base + lane*16)
#define GLDS16(g, l)                                                     \
    __builtin_amdgcn_global_load_lds(                                    \
        (const __attribute__((address_space(1))) void*)(g),              \
        (__attribute__((address_space(3))) void*)(l), 16, 0, 0)

// uniform cubic B-spline weights at r in [0,1)
__device__ __forceinline__ void spline_w(float r, float w[4]) {
    const float r2 = r * r, r3 = r2 * r;
    const float omr = 1.0f - r;
    w[0] = omr * omr * omr * (1.0f / 6.0f);
    w[1] = (3.0f * r3 - 6.0f * r2 + 4.0f) * (1.0f / 6.0f);
    w[2] = (-3.0f * r3 + 3.0f * r2 + 3.0f * r + 1.0f) * (1.0f / 6.0f);
    w[3] = r3 * (1.0f / 6.0f);
}

// ---------------------------------------------------------------------------
// coeffs fp32 -> bf16, stored with 16B-chunk XOR swizzle by (o&7) within each
// 64-elem i-block, so linear global_load_lds lands bank-conflict-free tiles.
// ---------------------------------------------------------------------------
__global__ void k_cvt(const float* __restrict__ src, __bf16* __restrict__ dst) {
    const size_t g   = blockIdx.x * blockDim.x + threadIdx.x;  // one per 8 elems
    const size_t idx = g * 8;
    const int i = (int)(idx & 1023);
    const int o = (int)((idx >> 10) & 1023);
    const int c = (i >> 3) & 7;                 // 16B chunk within 64-elem block
    const int isw = (i & ~63) | ((c ^ (o & 7)) << 3);
    f32x8 v = *(const f32x8*)(src + idx);
    bf16x8 ov = __builtin_convertvector(v, bf16x8);
    *(bf16x8*)(dst + (idx - i) + isw) = ov;
}

// ---------------------------------------------------------------------------
// basis kernel: A[b][n*1024 + swz(i)] = B_n(x[b,i]) in bf16, chunk-swizzled
// by (b&7).  4 i's per thread (stay within one 8-elem chunk).
// ---------------------------------------------------------------------------
__global__ void k_basis(const float* __restrict__ x, __bf16* __restrict__ A) {
    const int g    = blockIdx.x * blockDim.x + threadIdx.x;
    const int flat = g * 4;                       // [b][i] flat, i fastest
    const int b = flat >> 10, i = flat & 1023;
    f32x4 xv = *(const f32x4*)(x + flat);

    float w[4][4];
    int   jj[4];
#pragma unroll
    for (int e = 0; e < 4; ++e) {
        const float u  = (xv[e] + 2.5f) * 2.0f;   // knots [-1,1], h=0.5, t0=-2.5
        const float jf = floorf(u);
        jj[e] = (int)jf;
        spline_w(u - jf, w[e]);
    }

    const int c   = (i >> 3) & 7;
    const int isw = (i & ~63) | ((c ^ (b & 7)) << 3) | (i & 7);
    __bf16* base = A + (size_t)b * KTOT + isw;
#pragma unroll
    for (int n = 0; n < NB; ++n) {
        u16x4 pack;
#pragma unroll
        for (int e = 0; e < 4; ++e) {
            const int d = n - jj[e] + 3;          // which of the 4 weights
            float v = (d == 0) ? w[e][0]
                    : (d == 1) ? w[e][1]
                    : (d == 2) ? w[e][2]
                    : (d == 3) ? w[e][3] : 0.0f;
            __bf16 h = (__bf16)v;
            pack[e] = __builtin_bit_cast(unsigned short, h);
        }
        *(u16x4*)(base + n * IN_F) = pack;        // 8B store
    }
}

// ---------------------------------------------------------------------------
// bf16 GEMM, split-K x2: C[4096][1024] = A[4096][8192] * W^T.
// BM=256, BN=128, BK=64; 512 threads = 8 waves (4M x 2N), each wave 64x64 out
// as 2x2 tiles of v_mfma_f32_32x32x16_bf16 (16 ds_read_b128 + 16 MFMA per
// wave-step: 1.5x fewer LDS reads and 2x fewer MFMA instrs than 16x16 form).
// 3-deep LDS pipeline, counted vmcnt(6); XCD-aware 1-D grid decode;
// LDS tiles XOR-swizzled (chunk ^= row&7); sources pre-swizzled.
// A-frag: row=lane&31, k = 8*(lane>>5)+j (contig 16B).  B-frag mirrored.
// C/D: col=lane&31, row=(reg&3)+8*(reg>>2)+4*(lane>>5)  [m74/m101].
// ---------------------------------------------------------------------------
#define BM 256
#define BN 128
#define BK 64
#define NT (KTOT / BK)   // 128
#define SPLITK 2
#define NTS (NT / SPLITK)  // 64
#define BUFSZ 49152        // A 32K | B 16K

__global__ __launch_bounds__(512) void k_gemm(const __bf16* __restrict__ A,
                                              const __bf16* __restrict__ W,
                                              float* __restrict__ C,
                                              float* __restrict__ P) {
    __shared__ __align__(16) char ls[3 * BUFSZ];   // 144 KiB

    // XCD-aware decode: fid&7 = XCD (round-robin); same-y blocks colocate.
    const int fid = blockIdx.x;
    const int xcd = fid & 7;
    const int s   = fid >> 3;            // 0..31
    const int y   = xcd + 8 * (s & 1);   // 0..15  (A row-panel)
    const int xb  = (s >> 1) & 7;        // 0..7   (W col-panel)
    const int kz  = s >> 4;              // 0..1   (K split)

    const int o0   = xb * BN;
    const int b0   = y * BM;
    const int tid  = threadIdx.x;
    const int lane = tid & 63;
    const int wv   = tid >> 6;
    const int wr   = wv >> 1;          // wave row (0..3)
    const int wc   = wv & 1;           // wave col (0..1)
    const int l31  = lane & 31;
    const int kh   = lane >> 5;        // 0..1 (k-half of the 16-chunk)

    f32x16 acc[2][2] = {};

    const int srow  = tid >> 3;        // 0..63
    const int scol8 = (tid & 7) * 8;   // elem col within 64-elem k-row

    auto STAGE = [&](int buf, int kt) {
        const int k0 = kt * BK;
        const int n  = k0 >> 10;
        const int i0 = k0 & 1023;
        char* la = ls + buf * BUFSZ;
        char* lb = la + 32768;
#pragma unroll
        for (int it = 0; it < 4; ++it) {
            const __bf16* ga = A + (size_t)(b0 + srow + it * 64) * KTOT + k0 + scol8;
            GLDS16(ga, la + tid * 16 + it * 8192);
        }
#pragma unroll
        for (int it = 0; it < 2; ++it) {
            const __bf16* gw = W + ((size_t)n << 20)
                                 + (size_t)(o0 + srow + it * 64) * IN_F + i0 + scol8;
            GLDS16(gw, lb + tid * 16 + it * 8192);
        }
    };

    const int ktBeg = kz * NTS;
    STAGE(0, ktBeg);
    STAGE(1, ktBeg + 1);

    int cur = 0, nxt = 2;
    for (int t = 0; t < NTS; ++t) {
        // counted wait: tile t landed; tile t+1's 6 loads stay in flight
        if (t < NTS - 1) asm volatile("s_waitcnt vmcnt(6)" ::: "memory");
        else             asm volatile("s_waitcnt vmcnt(0)" ::: "memory");
        __builtin_amdgcn_s_barrier();
        __builtin_amdgcn_sched_barrier(0);

        if (t + 2 < NTS) STAGE(nxt, ktBeg + t + 2);

        const char* la = ls + cur * BUFSZ;
        const char* lb = la + 32768;
#pragma unroll
        for (int kk = 0; kk < BK; kk += 16) {
            bf16x8 af[2], bfr[2];
#pragma unroll
            for (int m = 0; m < 2; ++m) {
                const int r = wr * 64 + m * 32 + l31;
                const int c = ((kk >> 3) + kh) ^ (r & 7);
                af[m] = *(const bf16x8*)(la + r * 128 + c * 16);
            }
#pragma unroll
            for (int nn = 0; nn < 2; ++nn) {
                const int r = wc * 64 + nn * 32 + l31;
                const int c = ((kk >> 3) + kh) ^ (r & 7);
                bfr[nn] = *(const bf16x8*)(lb + r * 128 + c * 16);
            }
            __builtin_amdgcn_s_setprio(1);
#pragma unroll
            for (int m = 0; m < 2; ++m)
#pragma unroll
                for (int nn = 0; nn < 2; ++nn)
                    acc[m][nn] = __builtin_amdgcn_mfma_f32_32x32x16_bf16(
                        af[m], bfr[nn], acc[m][nn], 0, 0, 0);
            __builtin_amdgcn_s_setprio(0);
        }
        cur = (cur == 2) ? 0 : cur + 1;
        nxt = (nxt == 2) ? 0 : nxt + 1;
    }

    // epilogue: C/D layout col=lane&31, row=(reg&3)+8*(reg>>2)+4*(lane>>5)
    float* dst = (kz == 0) ? C : P;
#pragma unroll
    for (int m = 0; m < 2; ++m) {
#pragma unroll
        for (int nn = 0; nn < 2; ++nn) {
#pragma unroll
            for (int reg = 0; reg < 16; ++reg) {
                const int row = (reg & 3) + 8 * (reg >> 2) + 4 * kh;
                dst[(size_t)(b0 + wr * 64 + m * 32 + row) * OUT_F
                    + o0 + wc * 64 + nn * 32 + l31] = acc[m][nn][reg];
            }
        }
    }
}

// C += P, vectorized
__global__ void k_add(float* __restrict__ C, const float* __restrict__ P) {
    const size_t g = (size_t)(blockIdx.x * blockDim.x + threadIdx.x) * 4;
    f32x4 a = *(const f32x4*)(C + g);
    f32x4 b = *(const f32x4*)(P + g);
    a += b;
    *(f32x4*)(C + g) = a;
}

// ---------------------------------------------------------------------------
// slow-but-correct fallback (only if ws too small): fp32, no workspace
// ---------------------------------------------------------------------------
__global__ void k_naive(const float* __restrict__ x, const float* __restrict__ coeffs,
                        float* __restrict__ out) {
    const int b = blockIdx.y * 16 + (threadIdx.x >> 4);
    const int o = blockIdx.x * 16 + (threadIdx.x & 15);
    float sum = 0.0f;
    for (int i = 0; i < IN_F; ++i) {
        const float u  = (x[(size_t)b * IN_F + i] + 2.5f) * 2.0f;
        const float jf = floorf(u);
        const int   j  = (int)jf;
        float w[4];
        spline_w(u - jf, w);
#pragma unroll
        for (int m = 0; m < 4; ++m) {
            const int idx = j - 3 + m;
            if (idx >= 0 && idx < NB)
                sum += w[m] * coeffs[(size_t)idx * OUT_F * IN_F + (size_t)o * IN_F + i];
        }
    }
    out[(size_t)b * OUT_F + o] = sum;
}

// ---------------------------------------------------------------------------
extern "C" void kernel_launch(void* const* d_in, const int* in_sizes, int n_in,
                              void* d_out, int out_size, void* d_ws, size_t ws_size,
                              hipStream_t stream) {
    const float* x      = (const float*)d_in[0];
    // d_in[1] = knots: fixed linspace(-1,1,5) -> folded into constants
    const float* coeffs = (const float*)d_in[2];
    float* out = (float*)d_out;

    const size_t needA = (size_t)BATCH * KTOT * sizeof(__bf16);      // 64 MiB
    const size_t needW = (size_t)NB * OUT_F * IN_F * sizeof(__bf16); // 16 MiB
    const size_t needP = (size_t)BATCH * OUT_F * sizeof(float);      // 16 MiB

    if (ws_size >= needA + needW + needP) {
        __bf16* A  = (__bf16*)d_ws;
        __bf16* Wb = (__bf16*)((char*)d_ws + needA);
        float*  P  = (float*)((char*)d_ws + needA + needW);

        hipLaunchKernelGGL(k_cvt, dim3(NB * OUT_F * IN_F / 8 / 256), dim3(256), 0,
                           stream, coeffs, Wb);
        hipLaunchKernelGGL(k_basis, dim3(BATCH * IN_F / 4 / 256), dim3(256), 0,
                           stream, x, A);
        hipLaunchKernelGGL(k_gemm, dim3(256), dim3(512), 0, stream, A, Wb, out, P);
        hipLaunchKernelGGL(k_add, dim3(BATCH * OUT_F / 4 / 256), dim3(256), 0,
                           stream, out, P);
    } else {
        hipLaunchKernelGGL(k_naive, dim3(OUT_F / 16, BATCH / 16), dim3(256), 0,
                           stream, x, coeffs, out);
    }
}

// Round 7
// 120.554 us; speedup vs baseline: 1.0753x; 1.0753x over previous
//
#include <hip/hip_runtime.h>
#include <hip/hip_bf16.h>
#include <cstdint>
#include <cstddef>

#define IN_F   1024
#define OUT_F  1024
#define NB     8            // KNOT_COUNT + ORDER = 5 + 3
#define BATCH  4096
#define KTOT   (NB * IN_F)  // 8192

typedef __attribute__((ext_vector_type(4)))  float  f32x4;
typedef __attribute__((ext_vector_type(8)))  float  f32x8;
typedef __attribute__((ext_vector_type(8)))  __bf16 bf16x8;
typedef __attribute__((ext_vector_type(4)))  unsigned short u16x4;

// async global->LDS, 16B per lane (LDS dest = wave-uniform base + lane*16)
#define GLDS16(g, l)                                                     \
    __builtin_amdgcn_global_load_lds(                                    \
        (const __attribute__((address_space(1))) void*)(g),              \
        (__attribute__((address_space(3))) void*)(l), 16, 0, 0)

// uniform cubic B-spline weights at r in [0,1)
__device__ __forceinline__ void spline_w(float r, float w[4]) {
    const float r2 = r * r, r3 = r2 * r;
    const float omr = 1.0f - r;
    w[0] = omr * omr * omr * (1.0f / 6.0f);
    w[1] = (3.0f * r3 - 6.0f * r2 + 4.0f) * (1.0f / 6.0f);
    w[2] = (-3.0f * r3 + 3.0f * r2 + 3.0f * r + 1.0f) * (1.0f / 6.0f);
    w[3] = r3 * (1.0f / 6.0f);
}

// ---------------------------------------------------------------------------
// fused prep: blocks [0,4096) convert coeffs fp32->bf16 (16B-chunk XOR
// swizzle by o&7); blocks [4096,8192) compute basis A (swizzle by b&7).
// ---------------------------------------------------------------------------
__global__ void k_prep(const float* __restrict__ coeffs, __bf16* __restrict__ Wb,
                       const float* __restrict__ x, __bf16* __restrict__ A) {
    const int bb = blockIdx.x;
    if (bb < 4096) {
        const size_t g   = (size_t)bb * blockDim.x + threadIdx.x; // one per 8 elems
        const size_t idx = g * 8;
        const int i = (int)(idx & 1023);
        const int o = (int)((idx >> 10) & 1023);
        const int c = (i >> 3) & 7;
        const int isw = (i & ~63) | ((c ^ (o & 7)) << 3);
        f32x8 v = *(const f32x8*)(coeffs + idx);
        bf16x8 ov = __builtin_convertvector(v, bf16x8);
        *(bf16x8*)(Wb + (idx - i) + isw) = ov;
    } else {
        const int g    = (bb - 4096) * blockDim.x + threadIdx.x;
        const int flat = g * 4;                       // [b][i] flat, i fastest
        const int b = flat >> 10, i = flat & 1023;
        f32x4 xv = *(const f32x4*)(x + flat);

        float w[4][4];
        int   jj[4];
#pragma unroll
        for (int e = 0; e < 4; ++e) {
            const float u  = (xv[e] + 2.5f) * 2.0f;   // knots [-1,1], h=0.5
            const float jf = floorf(u);
            jj[e] = (int)jf;
            spline_w(u - jf, w[e]);
        }

        const int c   = (i >> 3) & 7;
        const int isw = (i & ~63) | ((c ^ (b & 7)) << 3) | (i & 7);
        __bf16* base = A + (size_t)b * KTOT + isw;
#pragma unroll
        for (int n = 0; n < NB; ++n) {
            u16x4 pack;
#pragma unroll
            for (int e = 0; e < 4; ++e) {
                const int d = n - jj[e] + 3;          // which of the 4 weights
                float v = (d == 0) ? w[e][0]
                        : (d == 1) ? w[e][1]
                        : (d == 2) ? w[e][2]
                        : (d == 3) ? w[e][3] : 0.0f;
                __bf16 h = (__bf16)v;
                pack[e] = __builtin_bit_cast(unsigned short, h);
            }
            *(u16x4*)(base + n * IN_F) = pack;        // 8B store
        }
    }
}

// ---------------------------------------------------------------------------
// bf16 GEMM, split-K x2: C[4096][1024] = A[4096][8192] * W^T.
// BM=256, BN=128, BK=64; 512 threads = 8 waves (4M x 2N), wave 64x64 out,
// 16x16x32 MFMA (verified layout).  3-deep LDS pipeline, counted vmcnt(6).
// PHASE-SPLIT K-step (T3/T5): per t, two phases {8 ds_read || half-STAGE ->
// barrier -> setprio MFMA x16 -> barrier}.  XCD-aware 1-D grid decode.
// LDS tiles XOR-swizzled (chunk ^= row&7); sources pre-swizzled.
// ---------------------------------------------------------------------------
#define BM 256
#define BN 128
#define BK 64
#define NT (KTOT / BK)     // 128
#define SPLITK 2
#define NTS (NT / SPLITK)  // 64
#define BUFSZ 49152        // A 32K | B 16K

__global__ __launch_bounds__(512) void k_gemm(const __bf16* __restrict__ A,
                                              const __bf16* __restrict__ W,
                                              float* __restrict__ C,
                                              float* __restrict__ P) {
    __shared__ __align__(16) char ls[3 * BUFSZ];   // 144 KiB

    // XCD-aware decode: fid&7 = XCD (round-robin); same-y blocks colocate.
    const int fid = blockIdx.x;
    const int xcd = fid & 7;
    const int s   = fid >> 3;            // 0..31
    const int y   = xcd + 8 * (s & 1);   // 0..15  (A row-panel)
    const int xb  = (s >> 1) & 7;        // 0..7   (W col-panel)
    const int kz  = s >> 4;              // 0..1   (K split)

    const int o0   = xb * BN;
    const int b0   = y * BM;
    const int tid  = threadIdx.x;
    const int lane = tid & 63;
    const int wv   = tid >> 6;
    const int wr   = wv >> 1;          // wave row (0..3)
    const int wc   = wv & 1;           // wave col (0..1)
    const int l15  = lane & 15;
    const int lhi  = lane >> 4;        // 0..3

    f32x4 acc[4][4] = {};

    const int srow  = tid >> 3;        // 0..63
    const int scol8 = (tid & 7) * 8;   // elem col within 64-elem k-row

    auto STAGE_A = [&](int buf, int kt) {
        const int k0 = kt * BK;
        char* la = ls + buf * BUFSZ;
#pragma unroll
        for (int it = 0; it < 4; ++it) {
            const __bf16* ga = A + (size_t)(b0 + srow + it * 64) * KTOT + k0 + scol8;
            GLDS16(ga, la + tid * 16 + it * 8192);
        }
    };
    auto STAGE_B = [&](int buf, int kt) {
        const int k0 = kt * BK;
        const int n  = k0 >> 10;
        const int i0 = k0 & 1023;
        char* lb = ls + buf * BUFSZ + 32768;
#pragma unroll
        for (int it = 0; it < 2; ++it) {
            const __bf16* gw = W + ((size_t)n << 20)
                                 + (size_t)(o0 + srow + it * 64) * IN_F + i0 + scol8;
            GLDS16(gw, lb + tid * 16 + it * 8192);
        }
    };

    const int ktBeg = kz * NTS;
    STAGE_A(0, ktBeg);     STAGE_B(0, ktBeg);
    STAGE_A(1, ktBeg + 1); STAGE_B(1, ktBeg + 1);

    int cur = 0, nxt = 2;
    for (int t = 0; t < NTS; ++t) {
        // counted wait: tile t landed; tile t+1's 6 loads stay in flight
        if (t < NTS - 1) asm volatile("s_waitcnt vmcnt(6)" ::: "memory");
        else             asm volatile("s_waitcnt vmcnt(0)" ::: "memory");
        __builtin_amdgcn_s_barrier();
        __builtin_amdgcn_sched_barrier(0);

        const char* la = ls + cur * BUFSZ;
        const char* lb = la + 32768;
        const bool doStage = (t + 2 < NTS);
        const int  kt2     = ktBeg + t + 2;

        // ---- phase 0: kk = 0 ----
        {
            bf16x8 af[4], bfr[4];
#pragma unroll
            for (int m = 0; m < 4; ++m) {
                const int r = wr * 64 + m * 16 + l15;
                const int c = lhi ^ (r & 7);
                af[m] = *(const bf16x8*)(la + r * 128 + c * 16);
            }
#pragma unroll
            for (int nn = 0; nn < 4; ++nn) {
                const int r = wc * 64 + nn * 16 + l15;
                const int c = lhi ^ (r & 7);
                bfr[nn] = *(const bf16x8*)(lb + r * 128 + c * 16);
            }
            if (doStage) STAGE_A(nxt, kt2);
            __builtin_amdgcn_s_barrier();
            __builtin_amdgcn_s_setprio(1);
#pragma unroll
            for (int m = 0; m < 4; ++m)
#pragma unroll
                for (int nn = 0; nn < 4; ++nn)
                    acc[m][nn] = __builtin_amdgcn_mfma_f32_16x16x32_bf16(
                        af[m], bfr[nn], acc[m][nn], 0, 0, 0);
            __builtin_amdgcn_s_setprio(0);
            __builtin_amdgcn_s_barrier();
        }
        // ---- phase 1: kk = 32 ----
        {
            bf16x8 af[4], bfr[4];
#pragma unroll
            for (int m = 0; m < 4; ++m) {
                const int r = wr * 64 + m * 16 + l15;
                const int c = (4 + lhi) ^ (r & 7);
                af[m] = *(const bf16x8*)(la + r * 128 + c * 16);
            }
#pragma unroll
            for (int nn = 0; nn < 4; ++nn) {
                const int r = wc * 64 + nn * 16 + l15;
                const int c = (4 + lhi) ^ (r & 7);
                bfr[nn] = *(const bf16x8*)(lb + r * 128 + c * 16);
            }
            if (doStage) STAGE_B(nxt, kt2);
            __builtin_amdgcn_s_barrier();
            __builtin_amdgcn_s_setprio(1);
#pragma unroll
            for (int m = 0; m < 4; ++m)
#pragma unroll
                for (int nn = 0; nn < 4; ++nn)
                    acc[m][nn] = __builtin_amdgcn_mfma_f32_16x16x32_bf16(
                        af[m], bfr[nn], acc[m][nn], 0, 0, 0);
            __builtin_amdgcn_s_setprio(0);
            // no trailing barrier: next t's vmcnt+barrier provides separation
        }
        cur = (cur == 2) ? 0 : cur + 1;
        nxt = (nxt == 2) ? 0 : nxt + 1;
    }

    // epilogue: C/D layout col = lane&15, row = (lane>>4)*4 + reg
    float* dst = (kz == 0) ? C : P;
    const int crow = lhi * 4;
#pragma unroll
    for (int m = 0; m < 4; ++m) {
#pragma unroll
        for (int nn = 0; nn < 4; ++nn) {
            float* cp = dst + (size_t)(b0 + wr * 64 + m * 16 + crow) * OUT_F
                            + o0 + wc * 64 + nn * 16 + l15;
#pragma unroll
            for (int j = 0; j < 4; ++j)
                cp[(size_t)j * OUT_F] = acc[m][nn][j];
        }
    }
}

// C += P, vectorized
__global__ void k_add(float* __restrict__ C, const float* __restrict__ P) {
    const size_t g = (size_t)(blockIdx.x * blockDim.x + threadIdx.x) * 4;
    f32x4 a = *(const f32x4*)(C + g);
    f32x4 b = *(const f32x4*)(P + g);
    a += b;
    *(f32x4*)(C + g) = a;
}

// ---------------------------------------------------------------------------
// slow-but-correct fallback (only if ws too small): fp32, no workspace
// ---------------------------------------------------------------------------
__global__ void k_naive(const float* __restrict__ x, const float* __restrict__ coeffs,
                        float* __restrict__ out) {
    const int b = blockIdx.y * 16 + (threadIdx.x >> 4);
    const int o = blockIdx.x * 16 + (threadIdx.x & 15);
    float sum = 0.0f;
    for (int i = 0; i < IN_F; ++i) {
        const float u  = (x[(size_t)b * IN_F + i] + 2.5f) * 2.0f;
        const float jf = floorf(u);
        const int   j  = (int)jf;
        float w[4];
        spline_w(u - jf, w);
#pragma unroll
        for (int m = 0; m < 4; ++m) {
            const int idx = j - 3 + m;
            if (idx >= 0 && idx < NB)
                sum += w[m] * coeffs[(size_t)idx * OUT_F * IN_F + (size_t)o * IN_F + i];
        }
    }
    out[(size_t)b * OUT_F + o] = sum;
}

// ---------------------------------------------------------------------------
extern "C" void kernel_launch(void* const* d_in, const int* in_sizes, int n_in,
                              void* d_out, int out_size, void* d_ws, size_t ws_size,
                              hipStream_t stream) {
    const float* x      = (const float*)d_in[0];
    // d_in[1] = knots: fixed linspace(-1,1,5) -> folded into constants
    const float* coeffs = (const float*)d_in[2];
    float* out = (float*)d_out;

    const size_t needA = (size_t)BATCH * KTOT * sizeof(__bf16);      // 64 MiB
    const size_t needW = (size_t)NB * OUT_F * IN_F * sizeof(__bf16); // 16 MiB
    const size_t needP = (size_t)BATCH * OUT_F * sizeof(float);      // 16 MiB

    if (ws_size >= needA + needW + needP) {
        __bf16* A  = (__bf16*)d_ws;
        __bf16* Wb = (__bf16*)((char*)d_ws + needA);
        float*  P  = (float*)((char*)d_ws + needA + needW);

        hipLaunchKernelGGL(k_prep, dim3(8192), dim3(256), 0, stream,
                           coeffs, Wb, x, A);
        hipLaunchKernelGGL(k_gemm, dim3(256), dim3(512), 0, stream, A, Wb, out, P);
        hipLaunchKernelGGL(k_add, dim3(BATCH * OUT_F / 4 / 256), dim3(256), 0,
                           stream, out, P);
    } else {
        hipLaunchKernelGGL(k_naive, dim3(OUT_F / 16, BATCH / 16), dim3(256), 0,
                           stream, x, coeffs, out);
    }
}